// Round 18
// baseline (375.773 us; speedup 1.0000x reference)
//
#include <hip/hip_runtime.h>
#include <hip/hip_bf16.h>

#define B_ 4
#define T_ 128
#define U_ 64
#define D_ 512
#define H_ 640
#define V_ 1024

typedef float f32x4 __attribute__((ext_vector_type(4)));

union U2L { uint2 u; long long l; };
union U4L2 { uint4 u; long long l[2]; };

// ---------------------------------------------------------------------------
// P0 fused prep (R13 config, measured ~9us):
//  blocks 0..95   : proj 8 rows each (bid<64: src->ps; 64..95: tgt->pt+b1)
//  blocks 96..175 : pack W2 -> fp8 e4m3 fragment cells, column-permuted
//    uint2 cell at [kq*1024 + wid*64 + (nf>>1)*32 + l16*2 + (nf&1)],
//    holding original col wid*64 + l16*4 + nf for k=8kq..8kq+7.
// ---------------------------------------------------------------------------
__global__ __launch_bounds__(640) void k_prep(
    const float* __restrict__ W2, uint2* __restrict__ w2p8,
    const int* __restrict__ slen, const int* __restrict__ tlen,
    float* __restrict__ out_tail,
    const float* __restrict__ src, const float* __restrict__ tgt,
    const float* __restrict__ W1, const float* __restrict__ b1,
    float* __restrict__ ps, float* __restrict__ pt) {
  __shared__ __align__(16) float lin[D_ * 8];    // 16KB
  int bid = blockIdx.x, tid = threadIdx.x;
  if (bid < 96) {
    bool is_t = bid >= 64;
    int r0 = (is_t ? (bid - 64) : bid) * 8;
    const float* in = (is_t ? tgt : src) + (size_t)r0 * D_;
    const float* w = is_t ? (W1 + (size_t)D_ * H_) : W1;
    float* outp = (is_t ? pt : ps) + (size_t)r0 * H_;
    for (int idx = tid; idx < 8 * D_; idx += 640) {
      int r = idx >> 9, k = idx & (D_ - 1);
      lin[k * 8 + r] = in[idx];
    }
    __syncthreads();
    float a[8];
    #pragma unroll
    for (int r = 0; r < 8; ++r) a[r] = 0.f;
    int j = tid;
    for (int k = 0; k < D_; ++k) {
      float wv = w[(size_t)k * H_ + j];
      f32x4 x0 = *(const f32x4*)&lin[k * 8];
      f32x4 x1 = *(const f32x4*)&lin[k * 8 + 4];
      a[0] += x0[0] * wv; a[1] += x0[1] * wv;
      a[2] += x0[2] * wv; a[3] += x0[3] * wv;
      a[4] += x1[0] * wv; a[5] += x1[1] * wv;
      a[6] += x1[2] * wv; a[7] += x1[3] * wv;
    }
    float bb = is_t ? b1[j] : 0.f;
    #pragma unroll
    for (int r = 0; r < 8; ++r) outp[(size_t)r * H_ + j] = a[r] + bb;
  } else {
    int kq = bid - 96;             // 0..79
    for (int idx = tid; idx < V_; idx += 640) {
      int wid = idx >> 6, rem = idx & 63, nf = rem >> 4, l16 = rem & 15;
      int col = wid * 64 + l16 * 4 + nf;
      float f[8];
      #pragma unroll
      for (int j = 0; j < 8; ++j) f[j] = W2[(size_t)(kq * 8 + j) * V_ + col];
      int d0 = __builtin_amdgcn_cvt_pk_fp8_f32(f[0], f[1], 0, 0);
      d0 = __builtin_amdgcn_cvt_pk_fp8_f32(f[2], f[3], d0, 1);
      int d1 = __builtin_amdgcn_cvt_pk_fp8_f32(f[4], f[5], 0, 0);
      d1 = __builtin_amdgcn_cvt_pk_fp8_f32(f[6], f[7], d1, 1);
      uint2 c; c.x = (unsigned)d0; c.y = (unsigned)d1;
      w2p8[(size_t)kq * 1024 + wid * 64 + (nf >> 1) * 32 + l16 * 2 + (nf & 1)] = c;
    }
    if (bid == 96 && tid < 8)
      out_tail[tid] = (tid < 4) ? (float)slen[tid] : (float)tlen[tid - 4];
  }
}

// ---------------------------------------------------------------------------
// Main: 512 blocks x 512 threads (8 waves, 2 blocks/CU); each block runs TWO
// tiles (uh=0,1) through a ROLLED loop (#pragma unroll 1). R17's identical
// structure spilled 413MB because full unroll let the scheduler hoist tile1's
// gen loads over tile0's store burst (transient >128 regs). The backward
// branch pins tile boundaries; all per-tile values (b2v, ptrow, arow, bp)
// are recomputed inside -- loop-carried state is ~6 scalars.
// Mechanism under test (R14/R15 differential): tile0's 67MB store burst
// drains under tile1's ~35us gen+K-loop instead of past kernel end.
// ---------------------------------------------------------------------------
__global__ __launch_bounds__(512, 4) void k_joint(
    const float* __restrict__ ps, const float* __restrict__ pt,
    const uint2* __restrict__ w2p8, const float* __restrict__ b2,
    float* __restrict__ out) {
  __shared__ uint2 ldsA[32 * 81];          // 20.7 KiB, [m][kq] padded rows
  __shared__ float red[8][32][2];          // 1 KiB
  __shared__ float lzs[32];
  int bid = blockIdx.x;                    // 0..511
  int xcd = bid & 7;
  int b = xcd >> 1;                        // one batch per XCD pair
  int t = (bid >> 3) + (xcd & 1) * 64;     // 0..127
  int tid = threadIdx.x;
  int lane = tid & 63, wid = tid >> 6;     // wid 0..7
  int l16 = lane & 15, lg = lane >> 4;
  int gm = tid >> 4, gk = tid & 15;
  const float* psrow = ps + (size_t)(b * T_ + t) * H_;

  #pragma unroll 1
  for (int uh = 0; uh < 2; ++uh) {
    if (uh) __syncthreads();               // protect ldsA from overwrite
    // ---- phase 1: A generation -> fp8 LDS; thread owns row gm (0..31) ----
    {
      const float* ptrow = pt + (size_t)(b * U_ + uh * 32 + gm) * H_;
      uint2* wrow = &ldsA[gm * 81];
      #pragma unroll
      for (int i = 0; i < 5; ++i) {
        int kq = i * 16 + gk;
        const float4* pp = (const float4*)(psrow + kq * 8);
        const float4* qq = (const float4*)(ptrow + kq * 8);
        float4 p0 = pp[0], p1 = pp[1];
        float4 q0 = qq[0], q1 = qq[1];
        float x[8] = {p0.x + q0.x, p0.y + q0.y, p0.z + q0.z, p0.w + q0.w,
                      p1.x + q1.x, p1.y + q1.y, p1.z + q1.z, p1.w + q1.w};
        float h[8];
        #pragma unroll
        for (int j = 0; j < 8; ++j) {
          float e = __expf(2.f * x[j]);
          h[j] = 1.f - 2.f * __builtin_amdgcn_rcpf(e + 1.f);
        }
        int d0 = __builtin_amdgcn_cvt_pk_fp8_f32(h[0], h[1], 0, 0);
        d0 = __builtin_amdgcn_cvt_pk_fp8_f32(h[2], h[3], d0, 1);
        int d1 = __builtin_amdgcn_cvt_pk_fp8_f32(h[4], h[5], 0, 0);
        d1 = __builtin_amdgcn_cvt_pk_fp8_f32(h[6], h[7], d1, 1);
        uint2 c; c.x = (unsigned)d0; c.y = (unsigned)d1;
        wrow[kq] = c;
      }
    }
    __syncthreads();

    f32x4 acc[2][8];
    #pragma unroll
    for (int mf = 0; mf < 2; ++mf)
      #pragma unroll
      for (int nf = 0; nf < 8; ++nf) {
        f32x4 z = {0.f, 0.f, 0.f, 0.f};
        acc[mf][nf] = z;
      }

    // ---- phase 2: K loop (20 iters of K=32); wave owns cols wid*128.. ----
    {
      const uint2* arow = ldsA + l16 * 81 + lg;
      const uint4* bp = (const uint4*)w2p8 + (size_t)lg * 512 + l16;
      for (int kq0 = 0; kq0 < 80; kq0 += 4) {
        U2L a[2];
        #pragma unroll
        for (int mf = 0; mf < 2; ++mf)
          a[mf].u = arow[mf * (16 * 81) + kq0];
        const uint4* bpi = bp + (size_t)kq0 * 512 + wid * 64;
        U4L2 q[4];
        q[0].u = bpi[0];                 // cols c0, nf 0,1
        q[1].u = bpi[16];                // cols c0, nf 2,3
        q[2].u = bpi[32];                // cols c1, nf 0,1
        q[3].u = bpi[48];                // cols c1, nf 2,3
        #pragma unroll
        for (int nf = 0; nf < 8; ++nf) {
          long long bl = q[nf >> 1].l[nf & 1];
          #pragma unroll
          for (int mf = 0; mf < 2; ++mf)
            acc[mf][nf] = __builtin_amdgcn_mfma_f32_16x16x32_fp8_fp8(
                a[mf].l, bl, acc[mf][nf], 0, 0, 0);
        }
      }
    }

    // ---- phase 3: fold b2 (reloaded per tile), softmax, f32x4 stores ----
    {
      f32x4 b2v0 = *(const f32x4*)&b2[wid * 128 + l16 * 4];
      f32x4 b2v1 = *(const f32x4*)&b2[wid * 128 + 64 + l16 * 4];
      #pragma unroll
      for (int mf = 0; mf < 2; ++mf)
        #pragma unroll
        for (int nf = 0; nf < 8; ++nf) {
          float bv = (nf < 4) ? b2v0[nf] : b2v1[nf - 4];
          #pragma unroll
          for (int r = 0; r < 4; ++r)
            acc[mf][nf][r] += bv;
        }
    }

    #pragma unroll
    for (int mf = 0; mf < 2; ++mf)
      #pragma unroll
      for (int r = 0; r < 4; ++r) {
        float pm = -3.4e38f;
        #pragma unroll
        for (int nf = 0; nf < 8; ++nf) pm = fmaxf(pm, acc[mf][nf][r]);
        pm = fmaxf(pm, __shfl_xor(pm, 1));
        pm = fmaxf(pm, __shfl_xor(pm, 2));
        pm = fmaxf(pm, __shfl_xor(pm, 4));
        pm = fmaxf(pm, __shfl_xor(pm, 8));
        float s = 0.f;
        #pragma unroll
        for (int nf = 0; nf < 8; ++nf) s += __expf(acc[mf][nf][r] - pm);
        s += __shfl_xor(s, 1);
        s += __shfl_xor(s, 2);
        s += __shfl_xor(s, 4);
        s += __shfl_xor(s, 8);
        if (l16 == 0) {
          int row = mf * 16 + lg * 4 + r;    // 0..31
          red[wid][row][0] = pm;
          red[wid][row][1] = s;
        }
      }
    __syncthreads();

    if (tid < 32) {
      float M = -3.4e38f;
      #pragma unroll
      for (int w8 = 0; w8 < 8; ++w8) M = fmaxf(M, red[w8][tid][0]);
      float S = 0.f;
      #pragma unroll
      for (int w8 = 0; w8 < 8; ++w8)
        S += red[w8][tid][1] * __expf(red[w8][tid][0] - M);
      lzs[tid] = M + __logf(S);
    }
    __syncthreads();

    float* outb = out + ((size_t)(b * T_ + t) * U_ + uh * 32) * V_;
    #pragma unroll
    for (int mf = 0; mf < 2; ++mf)
      #pragma unroll
      for (int r = 0; r < 4; ++r) {
        int row = mf * 16 + lg * 4 + r;
        float lz = lzs[row];
        f32x4 o0, o1;
        o0[0] = acc[mf][0][r] - lz;
        o0[1] = acc[mf][1][r] - lz;
        o0[2] = acc[mf][2][r] - lz;
        o0[3] = acc[mf][3][r] - lz;
        o1[0] = acc[mf][4][r] - lz;
        o1[1] = acc[mf][5][r] - lz;
        o1[2] = acc[mf][6][r] - lz;
        o1[3] = acc[mf][7][r] - lz;
        float* orow = outb + (size_t)row * V_ + wid * 128 + l16 * 4;
        *(f32x4*)orow = o0;
        *(f32x4*)(orow + 64) = o1;
      }
    // tile0 stores drain (L2->HBM) under tile1's gen + K-loop
  }
}

extern "C" void kernel_launch(void* const* d_in, const int* in_sizes, int n_in,
                              void* d_out, int out_size, void* d_ws, size_t ws_size,
                              hipStream_t stream) {
  const float* src = (const float*)d_in[0];
  const int*   slen = (const int*)d_in[1];
  const float* tgt = (const float*)d_in[2];
  const int*   tlen = (const int*)d_in[3];
  const float* W1 = (const float*)d_in[4];
  const float* b1 = (const float*)d_in[5];
  const float* W2 = (const float*)d_in[6];
  const float* b2 = (const float*)d_in[7];
  float* out = (float*)d_out;

  float* ps   = (float*)d_ws;                 // 512*640 f32
  float* pt   = ps + 512 * 640;               // 256*640 f32
  uint2* w2p8 = (uint2*)(pt + 256 * 640);     // 80*1024 uint2 (fp8 W2)

  k_prep<<<176, 640, 0, stream>>>(W2, w2p8, slen, tlen,
                                  out + (size_t)B_ * T_ * U_ * V_,
                                  src, tgt, W1, b1, ps, pt);
  k_joint<<<512, 512, 0, stream>>>(ps, pt, w2p8, b2, out);
}

// Round 19
// 93.565 us; speedup vs baseline: 4.0161x; 4.0161x over previous
//
#include <hip/hip_runtime.h>
#include <hip/hip_bf16.h>

#define B_ 4
#define T_ 128
#define U_ 64
#define D_ 512
#define H_ 640
#define V_ 1024

typedef float f32x4 __attribute__((ext_vector_type(4)));

union U2L { uint2 u; long long l; };
union U4L2 { uint4 u; long long l[2]; };

// ---------------------------------------------------------------------------
// P0 fused prep (R13 config, measured ~9us):
//  blocks 0..95   : proj 8 rows each (bid<64: src->ps; 64..95: tgt->pt+b1)
//  blocks 96..175 : pack W2 -> fp8 e4m3 fragment cells, column-permuted
//    uint2 cell at [kq*1024 + wid*64 + (nf>>1)*32 + l16*2 + (nf&1)],
//    holding original col wid*64 + l16*4 + nf for k=8kq..8kq+7.
// (R14 lesson: 16 rows/block kills the compiler's load pipelining -> 80us.)
// ---------------------------------------------------------------------------
__global__ __launch_bounds__(640) void k_prep(
    const float* __restrict__ W2, uint2* __restrict__ w2p8,
    const int* __restrict__ slen, const int* __restrict__ tlen,
    float* __restrict__ out_tail,
    const float* __restrict__ src, const float* __restrict__ tgt,
    const float* __restrict__ W1, const float* __restrict__ b1,
    float* __restrict__ ps, float* __restrict__ pt) {
  __shared__ __align__(16) float lin[D_ * 8];    // 16KB
  int bid = blockIdx.x, tid = threadIdx.x;
  if (bid < 96) {
    bool is_t = bid >= 64;
    int r0 = (is_t ? (bid - 64) : bid) * 8;
    const float* in = (is_t ? tgt : src) + (size_t)r0 * D_;
    const float* w = is_t ? (W1 + (size_t)D_ * H_) : W1;
    float* outp = (is_t ? pt : ps) + (size_t)r0 * H_;
    for (int idx = tid; idx < 8 * D_; idx += 640) {
      int r = idx >> 9, k = idx & (D_ - 1);
      lin[k * 8 + r] = in[idx];
    }
    __syncthreads();
    float a[8];
    #pragma unroll
    for (int r = 0; r < 8; ++r) a[r] = 0.f;
    int j = tid;
    for (int k = 0; k < D_; ++k) {
      float wv = w[(size_t)k * H_ + j];
      f32x4 x0 = *(const f32x4*)&lin[k * 8];
      f32x4 x1 = *(const f32x4*)&lin[k * 8 + 4];
      a[0] += x0[0] * wv; a[1] += x0[1] * wv;
      a[2] += x0[2] * wv; a[3] += x0[3] * wv;
      a[4] += x1[0] * wv; a[5] += x1[1] * wv;
      a[6] += x1[2] * wv; a[7] += x1[3] * wv;
    }
    float bb = is_t ? b1[j] : 0.f;
    #pragma unroll
    for (int r = 0; r < 8; ++r) outp[(size_t)r * H_ + j] = a[r] + bb;
  } else {
    int kq = bid - 96;             // 0..79
    for (int idx = tid; idx < V_; idx += 640) {
      int wid = idx >> 6, rem = idx & 63, nf = rem >> 4, l16 = rem & 15;
      int col = wid * 64 + l16 * 4 + nf;
      float f[8];
      #pragma unroll
      for (int j = 0; j < 8; ++j) f[j] = W2[(size_t)(kq * 8 + j) * V_ + col];
      int d0 = __builtin_amdgcn_cvt_pk_fp8_f32(f[0], f[1], 0, 0);
      d0 = __builtin_amdgcn_cvt_pk_fp8_f32(f[2], f[3], d0, 1);
      int d1 = __builtin_amdgcn_cvt_pk_fp8_f32(f[4], f[5], 0, 0);
      d1 = __builtin_amdgcn_cvt_pk_fp8_f32(f[6], f[7], d1, 1);
      uint2 c; c.x = (unsigned)d0; c.y = (unsigned)d1;
      w2p8[(size_t)kq * 1024 + wid * 64 + (nf >> 1) * 32 + l16 * 2 + (nf & 1)] = c;
    }
    if (bid == 96 && tid < 8)
      out_tail[tid] = (tid < 4) ? (float)slen[tid] : (float)tlen[tid - 4];
  }
}

// ---------------------------------------------------------------------------
// Main (best measured: 94.0us total, R15): 1024 blocks x 512 threads (8
// waves), TWO blocks co-resident per CU. Inter-block phase overlap: while
// block A runs serial gen/softmax (VALU), block B's K-loop feeds the MFMA
// pipe (R11 -> R14: 78 -> 38us compute, the session's key win).
// Block = 32 u-rows x full V (block-local softmax); wave owns 128 cols:
// acc[2][8]=64 AGPR + 64 working VGPR = exactly the 128-reg cap at 4
// waves/SIMD. ZERO loop-carried state (R4/R13/R17/R18: any addition spills
// ~410MB to scratch, 4x slowdown). fp8 e4m3 A and W2 (absmax 0.156 vs 2.24
// threshold). nt f32x4 stores (R16: nt-vs-cached null).
// Remaining ~47us/replay is end-of-round write-burst drain exposed at the
// replay boundary -- structural to last-axis log_softmax (write-at-end);
// all in-block spreading variants hit the register wall.
// ---------------------------------------------------------------------------
__global__ __launch_bounds__(512, 4) void k_joint(
    const float* __restrict__ ps, const float* __restrict__ pt,
    const uint2* __restrict__ w2p8, const float* __restrict__ b2,
    float* __restrict__ out) {
  __shared__ uint2 ldsA[32 * 81];          // 20.7 KiB, [m][kq] padded rows
  __shared__ float red[8][32][2];          // 1 KiB
  __shared__ float lzs[32];
  int bid = blockIdx.x;                    // 0..1023
  int xcd = bid & 7;
  int b = xcd >> 1;                        // one batch per XCD pair
  int rest = bid >> 3;                     // 0..127
  int t = (rest & 63) + (xcd & 1) * 64;    // 0..127
  int uh = rest >> 6;                      // u-half 0/1
  int tid = threadIdx.x;
  int lane = tid & 63, wid = tid >> 6;     // wid 0..7
  int l16 = lane & 15, lg = lane >> 4;
  const float* psrow = ps + (size_t)(b * T_ + t) * H_;

  // ---- phase 1: A generation -> fp8 LDS; thread owns row gm (0..31) ----
  {
    int gm = tid >> 4, gk = tid & 15;
    const float* ptrow = pt + (size_t)(b * U_ + uh * 32 + gm) * H_;
    uint2* wrow = &ldsA[gm * 81];
    #pragma unroll
    for (int i = 0; i < 5; ++i) {
      int kq = i * 16 + gk;
      const float4* pp = (const float4*)(psrow + kq * 8);
      const float4* qq = (const float4*)(ptrow + kq * 8);
      float4 p0 = pp[0], p1 = pp[1];
      float4 q0 = qq[0], q1 = qq[1];
      float x[8] = {p0.x + q0.x, p0.y + q0.y, p0.z + q0.z, p0.w + q0.w,
                    p1.x + q1.x, p1.y + q1.y, p1.z + q1.z, p1.w + q1.w};
      float h[8];
      #pragma unroll
      for (int j = 0; j < 8; ++j) {
        float e = __expf(2.f * x[j]);
        h[j] = 1.f - 2.f * __builtin_amdgcn_rcpf(e + 1.f);
      }
      int d0 = __builtin_amdgcn_cvt_pk_fp8_f32(h[0], h[1], 0, 0);
      d0 = __builtin_amdgcn_cvt_pk_fp8_f32(h[2], h[3], d0, 1);
      int d1 = __builtin_amdgcn_cvt_pk_fp8_f32(h[4], h[5], 0, 0);
      d1 = __builtin_amdgcn_cvt_pk_fp8_f32(h[6], h[7], d1, 1);
      uint2 c; c.x = (unsigned)d0; c.y = (unsigned)d1;
      wrow[kq] = c;
    }
  }
  __syncthreads();

  f32x4 acc[2][8];
  #pragma unroll
  for (int mf = 0; mf < 2; ++mf)
    #pragma unroll
    for (int nf = 0; nf < 8; ++nf) {
      f32x4 z = {0.f, 0.f, 0.f, 0.f};
      acc[mf][nf] = z;
    }

  // ---- phase 2: K loop (20 iters of K=32); wave owns cols wid*128.. ----
  {
    const uint2* arow = ldsA + l16 * 81 + lg;
    const uint4* bp = (const uint4*)w2p8 + (size_t)lg * 512 + l16;
    for (int kq0 = 0; kq0 < 80; kq0 += 4) {
      U2L a[2];
      #pragma unroll
      for (int mf = 0; mf < 2; ++mf)
        a[mf].u = arow[mf * (16 * 81) + kq0];
      const uint4* bpi = bp + (size_t)kq0 * 512 + wid * 64;
      U4L2 q[4];
      q[0].u = bpi[0];                 // cols c0, nf 0,1
      q[1].u = bpi[16];                // cols c0, nf 2,3
      q[2].u = bpi[32];                // cols c1, nf 0,1
      q[3].u = bpi[48];                // cols c1, nf 2,3
      #pragma unroll
      for (int nf = 0; nf < 8; ++nf) {
        long long bl = q[nf >> 1].l[nf & 1];
        #pragma unroll
        for (int mf = 0; mf < 2; ++mf)
          acc[mf][nf] = __builtin_amdgcn_mfma_f32_16x16x32_fp8_fp8(
              a[mf].l, bl, acc[mf][nf], 0, 0, 0);
      }
    }
  }

  // ---- phase 3: fold b2 (permuted within each 64-col block), softmax ----
  {
    f32x4 b2v0 = *(const f32x4*)&b2[wid * 128 + l16 * 4];
    f32x4 b2v1 = *(const f32x4*)&b2[wid * 128 + 64 + l16 * 4];
    #pragma unroll
    for (int mf = 0; mf < 2; ++mf)
      #pragma unroll
      for (int nf = 0; nf < 8; ++nf) {
        float bv = (nf < 4) ? b2v0[nf] : b2v1[nf - 4];
        #pragma unroll
        for (int r = 0; r < 4; ++r)
          acc[mf][nf][r] += bv;
      }
  }

  #pragma unroll
  for (int mf = 0; mf < 2; ++mf)
    #pragma unroll
    for (int r = 0; r < 4; ++r) {
      float pm = -3.4e38f;
      #pragma unroll
      for (int nf = 0; nf < 8; ++nf) pm = fmaxf(pm, acc[mf][nf][r]);
      pm = fmaxf(pm, __shfl_xor(pm, 1));
      pm = fmaxf(pm, __shfl_xor(pm, 2));
      pm = fmaxf(pm, __shfl_xor(pm, 4));
      pm = fmaxf(pm, __shfl_xor(pm, 8));
      float s = 0.f;
      #pragma unroll
      for (int nf = 0; nf < 8; ++nf) s += __expf(acc[mf][nf][r] - pm);
      s += __shfl_xor(s, 1);
      s += __shfl_xor(s, 2);
      s += __shfl_xor(s, 4);
      s += __shfl_xor(s, 8);
      if (l16 == 0) {
        int row = mf * 16 + lg * 4 + r;    // 0..31
        red[wid][row][0] = pm;
        red[wid][row][1] = s;
      }
    }
  __syncthreads();

  if (tid < 32) {
    float M = -3.4e38f;
    #pragma unroll
    for (int w8 = 0; w8 < 8; ++w8) M = fmaxf(M, red[w8][tid][0]);
    float S = 0.f;
    #pragma unroll
    for (int w8 = 0; w8 < 8; ++w8)
      S += red[w8][tid][1] * __expf(red[w8][tid][0] - M);
    lzs[tid] = M + __logf(S);
  }
  __syncthreads();

  float* outb = out + ((size_t)(b * T_ + t) * U_ + uh * 32) * V_;
  #pragma unroll
  for (int mf = 0; mf < 2; ++mf)
    #pragma unroll
    for (int r = 0; r < 4; ++r) {
      int row = mf * 16 + lg * 4 + r;
      float lz = lzs[row];
      f32x4 o0, o1;
      o0[0] = acc[mf][0][r] - lz;
      o0[1] = acc[mf][1][r] - lz;
      o0[2] = acc[mf][2][r] - lz;
      o0[3] = acc[mf][3][r] - lz;
      o1[0] = acc[mf][4][r] - lz;
      o1[1] = acc[mf][5][r] - lz;
      o1[2] = acc[mf][6][r] - lz;
      o1[3] = acc[mf][7][r] - lz;
      float* orow = outb + (size_t)row * V_ + wid * 128 + l16 * 4;
      __builtin_nontemporal_store(o0, (f32x4*)orow);
      __builtin_nontemporal_store(o1, (f32x4*)(orow + 64));
    }
}

extern "C" void kernel_launch(void* const* d_in, const int* in_sizes, int n_in,
                              void* d_out, int out_size, void* d_ws, size_t ws_size,
                              hipStream_t stream) {
  const float* src = (const float*)d_in[0];
  const int*   slen = (const int*)d_in[1];
  const float* tgt = (const float*)d_in[2];
  const int*   tlen = (const int*)d_in[3];
  const float* W1 = (const float*)d_in[4];
  const float* b1 = (const float*)d_in[5];
  const float* W2 = (const float*)d_in[6];
  const float* b2 = (const float*)d_in[7];
  float* out = (float*)d_out;

  float* ps   = (float*)d_ws;                 // 512*640 f32
  float* pt   = ps + 512 * 640;               // 256*640 f32
  uint2* w2p8 = (uint2*)(pt + 256 * 640);     // 80*1024 uint2 (fp8 W2)

  k_prep<<<176, 640, 0, stream>>>(W2, w2p8, slen, tlen,
                                  out + (size_t)B_ * T_ * U_ * V_,
                                  src, tgt, W1, b1, ps, pt);
  k_joint<<<1024, 512, 0, stream>>>(ps, pt, w2p8, b2, out);
}